// Round 10
// baseline (125.120 us; speedup 1.0000x reference)
//
#include <hip/hip_runtime.h>
#include <math.h>

#define ATOM 64
#define AS1 __attribute__((address_space(1)))
#define AS3 __attribute__((address_space(3)))

__device__ __forceinline__ void gl16(const void* g, void* l) {
    __builtin_amdgcn_global_load_lds((const AS1 void*)g, (AS3 void*)l, 16, 0, 0);
}
__device__ __forceinline__ void gl4(const void* g, void* l) {
    __builtin_amdgcn_global_load_lds((const AS1 void*)g, (AS3 void*)l, 4, 0, 0);
}

// ===========================================================================
// full per-thread MLP head: x[20] -> 32 -> 32 -> 1 (bias3 added by caller)
// ===========================================================================
__device__ __forceinline__ float full_head(const float (&x)[20],
                                           const float* __restrict__ w1, const float* __restrict__ b1,
                                           const float* __restrict__ w2, const float* __restrict__ b2,
                                           const float* __restrict__ w3)
{
    float h1[32];
#pragma unroll
    for (int q=0;q<8;++q) {
        float4 b = *(const float4*)(b1 + 4*q);
        h1[4*q+0]=b.x; h1[4*q+1]=b.y; h1[4*q+2]=b.z; h1[4*q+3]=b.w;
    }
#pragma unroll
    for (int d=0; d<20; ++d) {
        const float xv = x[d];
        const float* row = w1 + d*32;
#pragma unroll
        for (int q=0;q<8;++q) {
            float4 w = *(const float4*)(row + 4*q);
            h1[4*q+0] += xv*w.x; h1[4*q+1] += xv*w.y;
            h1[4*q+2] += xv*w.z; h1[4*q+3] += xv*w.w;
        }
    }
    float p[32];
#pragma unroll
    for (int q=0;q<8;++q) {
        float4 b = *(const float4*)(b2 + 4*q);
        p[4*q+0]=b.x; p[4*q+1]=b.y; p[4*q+2]=b.z; p[4*q+3]=b.w;
    }
#pragma unroll
    for (int o=0;o<32;++o) {
        const float hv = fmaxf(h1[o], 0.f);
        const float* row = w2 + o*32;
#pragma unroll
        for (int q=0;q<8;++q) {
            float4 w = *(const float4*)(row + 4*q);
            p[4*q+0] += hv*w.x; p[4*q+1] += hv*w.y;
            p[4*q+2] += hv*w.z; p[4*q+3] += hv*w.w;
        }
    }
    float s = 0.f;
#pragma unroll
    for (int q=0;q<8;++q) {
        float4 wq = *(const float4*)(w3 + 4*q);
        s += fmaxf(p[4*q+0], 0.f)*wq.x;
        s += fmaxf(p[4*q+1], 0.f)*wq.y;
        s += fmaxf(p[4*q+2], 0.f)*wq.z;
        s += fmaxf(p[4*q+3], 0.f)*wq.w;
    }
    return s;
}

// ===========================================================================
// R10 Kernel 1: k_embed — DMA-staged (global_load_lds), double-buffered.
// 64 actions/block, 1 action/quad, atoms in 8 eighths of 8.
// Per eighth, 40 DMA instructions (10/wave): R 8x w16 rows (stride 66 f4),
// M 24x w4 dword-rows (stride 68 f), S 8x w4 rows (stride 68 f).
// Counted vmcnt(10) + raw s_barrier keeps next eighth in flight over compute.
// ===========================================================================
__global__ __launch_bounds__(256) void k_embed(
    const float* __restrict__ Smat, const float* __restrict__ Rraw, const float* __restrict__ Mspec,
    const float* __restrict__ We1, const float* __restrict__ be1,
    float* __restrict__ Vws, float* __restrict__ A0ws, int n)
{
    __shared__ __align__(16) float4 lds_R[2][8*66];    // 16896 B
    __shared__ __align__(16) float  lds_M[2][24*68];   // 13056 B
    __shared__ __align__(16) float  lds_S[2][8*68];    //  4352 B

    const int tid  = threadIdx.x;
    const int w    = tid >> 6;
    const int lane = tid & 63;
    const int j    = tid & 3;
    const int grp  = tid >> 2;
    const int act0 = blockIdx.x*64;
    const int act  = act0 + grp;
    const bool active = act < n;

    // e1 weights: uniform -> scalar regs
    float e1w0[10], e1w1[10], e1w2[10], e1w3[10];
#pragma unroll
    for (int e=0;e<10;++e){
        e1w0[e]=be1[e]; e1w1[e]=We1[e]; e1w2[e]=We1[10+e]; e1w3[e]=We1[20+e];
    }

    // per-lane global bases (lane covers action act0+lane for DMA source)
    const int arow = min(act0 + lane, n-1);
    const char* gRb = (const char*)Rraw  + (size_t)arow*1024;  // 64 atoms * 16B
    const char* gSb = (const char*)Smat  + (size_t)arow*256;   // 64 * 4B
    const char* gMb = (const char*)Mspec + (size_t)arow*768;   // 192 * 4B

    float Bh[4][10];
    float Rsum[4] = {0.f,0.f,0.f,0.f};
#pragma unroll
    for (int l=0;l<4;++l)
#pragma unroll
        for (int e=0;e<10;++e) Bh[l][e]=0.f;

    float a0h[10], a0r[4];
#pragma unroll
    for (int e=0;e<10;++e) a0h[e]=0.f;
    a0r[0]=a0r[1]=a0r[2]=a0r[3]=0.f;

    auto issue = [&](int c, int b){
        const char* r = gRb + c*128;   // eighth c: atoms 8c.., 8*16B
        const char* m = gMb + c*96;    // 24 dwords
        const char* s = gSb + c*32;    // 8 dwords
#pragma unroll 1
        for (int it = w; it < 40; it += 4) {
            if (it < 8) {
                gl16(r + it*16, &lds_R[b][it*66]);
            } else if (it < 32) {
                gl4(m + (it-8)*4, &lds_M[b][(it-8)*68]);
            } else {
                gl4(s + (it-32)*4, &lds_S[b][(it-32)*68]);
            }
        }
    };

    auto compute = [&](int b, bool first){
#pragma unroll
        for (int u=0; u<2; ++u){
            const int t = 4*u + j;                  // atom-in-eighth owned by lane j
            const float4 r = lds_R[b][t*66 + grp];
            const float  s = lds_S[b][t*68 + grp];
            const float  m0 = lds_M[b][(3*t+0)*68 + grp];
            const float  m1 = lds_M[b][(3*t+1)*68 + grp];
            const float  m2 = lds_M[b][(3*t+2)*68 + grp];

            const float Rl0=s*r.x, Rl1=s*r.y, Rl2=s*r.z, Rl3=s*r.w;
            const float sg0=s*m0, sg1=s*m1, sg2=s*m2;
            float h[10];
#pragma unroll
            for (int e=0;e<10;++e)
                h[e] = fmaxf(0.f, e1w0[e] + sg0*e1w1[e] + sg1*e1w2[e] + sg2*e1w3[e]);
            Rsum[0]+=Rl0; Rsum[1]+=Rl1; Rsum[2]+=Rl2; Rsum[3]+=Rl3;
#pragma unroll
            for (int e=0;e<10;++e){
                const float he=h[e];
                Bh[0][e]+=Rl0*he; Bh[1][e]+=Rl1*he; Bh[2][e]+=Rl2*he; Bh[3][e]+=Rl3*he;
            }
            if (first && u==0 && j==0){             // global atom 0 of this action
#pragma unroll
                for (int e=0;e<10;++e) a0h[e]=h[e];
                a0r[0]=Rl0; a0r[1]=Rl1; a0r[2]=Rl2; a0r[3]=Rl3;
            }
        }
    };

    // prologue
    issue(0, 0);
    asm volatile("s_waitcnt vmcnt(0)" ::: "memory");
    __builtin_amdgcn_s_barrier();

#pragma unroll 1
    for (int c=0; c<8; ++c){
        if (c < 7) {
            issue(c+1, (c+1)&1);
            asm volatile("s_waitcnt vmcnt(10)" ::: "memory");   // batch c done; c+1 in flight
        } else {
            asm volatile("s_waitcnt vmcnt(0)" ::: "memory");
        }
        __builtin_amdgcn_s_barrier();       // batch c visible to all waves
        compute(c&1, c==0);
        asm volatile("s_waitcnt lgkmcnt(0)" ::: "memory");
        __builtin_amdgcn_s_barrier();       // everyone done reading buf[c&1]
    }

    // quad butterfly-reduce the 44 accumulators
#pragma unroll
    for (int l=0;l<4;++l) {
        float v=Rsum[l]; v+=__shfl_xor(v,1); v+=__shfl_xor(v,2); Rsum[l]=v;
#pragma unroll
        for (int e=0;e<10;++e) {
            float ww=Bh[l][e]; ww+=__shfl_xor(ww,1); ww+=__shfl_xor(ww,2); Bh[l][e]=ww;
        }
    }

    if (!active) return;
    const size_t N = (size_t)n;
    if (j==0) {
#pragma unroll
        for (int e=0;e<10;++e) Vws[(size_t)e*N + act] = Bh[0][e];
        Vws[(size_t)40*N + act] = Rsum[0];
#pragma unroll
        for (int e=0;e<10;++e) A0ws[(size_t)e*N + act] = a0h[e];
#pragma unroll
        for (int l=0;l<4;++l)  A0ws[(size_t)(10+l)*N + act] = a0r[l];
    } else if (j==1) {
#pragma unroll
        for (int e=0;e<10;++e) Vws[(size_t)(10+e)*N + act] = Bh[1][e];
        Vws[(size_t)41*N + act] = Rsum[1];
    } else if (j==2) {
#pragma unroll
        for (int e=0;e<10;++e) Vws[(size_t)(20+e)*N + act] = Bh[2][e];
        Vws[(size_t)42*N + act] = Rsum[2];
    } else {
#pragma unroll
        for (int e=0;e<10;++e) Vws[(size_t)(30+e)*N + act] = Bh[3][e];
        Vws[(size_t)43*N + act] = Rsum[3];
    }
}

// ===========================================================================
// Kernel 2: k_head — D construction + both MLP heads.
// Block = 256 threads = 128 actions x 2 heads (tid<128 policy, >=128 value).
// ===========================================================================
__global__ __launch_bounds__(256) void k_head(
    const float* __restrict__ Vws, const float* __restrict__ A0ws,
    const float* __restrict__ We2, const float* __restrict__ be2,
    const float* __restrict__ Wf1, const float* __restrict__ bf1,
    const float* __restrict__ Wf2, const float* __restrict__ bf2,
    const float* __restrict__ Wf3, const float* __restrict__ bf3,
    const float* __restrict__ Wv1, const float* __restrict__ bv1,
    const float* __restrict__ Wv2, const float* __restrict__ bv2,
    const float* __restrict__ Wv3, const float* __restrict__ bv3,
    float* __restrict__ logits, float* __restrict__ pmax,
    float* __restrict__ psum, float* __restrict__ pval, int n)
{
    __shared__ __align__(16) float s_e2[10][12];
    __shared__ __align__(16) float s_f1[640], s_v1[640];
    __shared__ __align__(16) float s_f2[1024], s_v2[1024];
    __shared__ __align__(16) float s_b1[32], s_b2[32], s_f3[32];
    __shared__ __align__(16) float s_bv1[32], s_bv2[32], s_v3[32];
    __shared__ float red_l[128], red_v[128];

    const int tid = threadIdx.x;
    for (int i=tid;i<640;i+=256){ s_f1[i]=Wf1[i]; s_v1[i]=Wv1[i]; }
    for (int i=tid;i<1024;i+=256){ s_f2[i]=Wf2[i]; s_v2[i]=Wv2[i]; }
    if (tid<32){ s_b1[tid]=bf1[tid]; s_b2[tid]=bf2[tid]; s_f3[tid]=Wf3[tid];
                 s_bv1[tid]=bv1[tid]; s_bv2[tid]=bv2[tid]; s_v3[tid]=Wv3[tid]; }
    if (tid<10){
        s_e2[tid][0] = be2[tid];
        for (int e=0;e<10;++e) s_e2[tid][1+e] = We2[e*10+tid];
        s_e2[tid][11] = 0.f;
    }
    __syncthreads();

    const int half = tid >> 7;
    const int idx  = tid & 127;
    const int act  = blockIdx.x*128 + idx;
    const bool active = act < n;
    const int actc = active ? act : (n-1);
    const size_t N = (size_t)n;

    float Bh[4][10], Rsum[4];
#pragma unroll
    for (int l=0;l<4;++l)
#pragma unroll
        for (int e=0;e<10;++e) Bh[l][e] = Vws[(size_t)(l*10+e)*N + actc];
#pragma unroll
    for (int l=0;l<4;++l) Rsum[l] = Vws[(size_t)(40+l)*N + actc];

    if (half) {
        float h0[10], r0[4];
#pragma unroll
        for (int e=0;e<10;++e) h0[e] = A0ws[(size_t)e*N + actc];
#pragma unroll
        for (int l=0;l<4;++l)  r0[l] = A0ws[(size_t)(10+l)*N + actc];
#pragma unroll
        for (int l=0;l<4;++l){
            Rsum[l] -= r0[l];
#pragma unroll
            for (int e=0;e<10;++e) Bh[l][e] -= r0[l]*h0[e];
        }
    }

    float Bk0[4], Bk1[4];
#pragma unroll
    for (int k=0;k<2;++k){
        const float4 c0 = *(const float4*)&s_e2[k][0];
        const float4 c1 = *(const float4*)&s_e2[k][4];
        const float4 c2 = *(const float4*)&s_e2[k][8];
#pragma unroll
        for (int l=0;l<4;++l){
            const float v = Rsum[l]*c0.x + Bh[l][0]*c0.y + Bh[l][1]*c0.z + Bh[l][2]*c0.w
                          + Bh[l][3]*c1.x + Bh[l][4]*c1.y + Bh[l][5]*c1.z + Bh[l][6]*c1.w
                          + Bh[l][7]*c2.x + Bh[l][8]*c2.y + Bh[l][9]*c2.z;
            if (k==0) Bk0[l]=v; else Bk1[l]=v;
        }
    }
    float D[20];
#pragma unroll
    for (int q=0;q<10;++q){
        const float4 c0 = *(const float4*)&s_e2[q][0];
        const float4 c1 = *(const float4*)&s_e2[q][4];
        const float4 c2 = *(const float4*)&s_e2[q][8];
        float Bq[4];
#pragma unroll
        for (int l=0;l<4;++l)
            Bq[l] = Rsum[l]*c0.x + Bh[l][0]*c0.y + Bh[l][1]*c0.z + Bh[l][2]*c0.w
                  + Bh[l][3]*c1.x + Bh[l][4]*c1.y + Bh[l][5]*c1.z + Bh[l][6]*c1.w
                  + Bh[l][7]*c2.x + Bh[l][8]*c2.y + Bh[l][9]*c2.z;
        D[q]    = Bk0[0]*Bq[0]+Bk0[1]*Bq[1]+Bk0[2]*Bq[2]+Bk0[3]*Bq[3];
        D[10+q] = Bk1[0]*Bq[0]+Bk1[1]*Bq[1]+Bk1[2]*Bq[2]+Bk1[3]*Bq[3];
    }

    const float* w1 = half ? s_v1  : s_f1;
    const float* b1 = half ? s_bv1 : s_b1;
    const float* w2 = half ? s_v2  : s_f2;
    const float* b2 = half ? s_bv2 : s_b2;
    const float* w3 = half ? s_v3  : s_f3;
    const float  b3 = half ? bv3[0] : bf3[0];
    const float  out = full_head(D, w1, b1, w2, b2, w3) + b3;

    if (half == 0) {
        red_l[idx] = active ? out : -INFINITY;
        if (active) logits[act] = out;
    } else {
        red_v[idx] = active ? out : 0.f;
    }
    __syncthreads();

    if (tid < 64) {
        float m = fmaxf(red_l[tid], red_l[tid+64]);
#pragma unroll
        for (int k=1;k<64;k<<=1) m = fmaxf(m, __shfl_xor(m,k));
        float ssum = expf(red_l[tid]-m) + expf(red_l[tid+64]-m);
        float vsum = red_v[tid] + red_v[tid+64];
#pragma unroll
        for (int k=1;k<64;k<<=1){ ssum += __shfl_xor(ssum,k); vsum += __shfl_xor(vsum,k); }
        if (tid==0){ pmax[blockIdx.x]=m; psum[blockIdx.x]=ssum; pval[blockIdx.x]=vsum; }
    }
}

// ===========================================================================
// Fused fallback (R3 structure, plain 256 bound)
// ===========================================================================
__device__ __forceinline__ void make_D(const float (&Bh)[4][10], const float (&Rsum)[4],
                                       const float (*e2)[12], float (&D)[20])
{
    float Bk[2][4];
#pragma unroll
    for (int k=0;k<2;++k) {
        const float4 c0 = *(const float4*)&e2[k][0];
        const float4 c1 = *(const float4*)&e2[k][4];
        const float4 c2 = *(const float4*)&e2[k][8];
#pragma unroll
        for (int l=0;l<4;++l) {
            Bk[k][l] = Rsum[l]*c0.x + Bh[l][0]*c0.y + Bh[l][1]*c0.z + Bh[l][2]*c0.w
                     + Bh[l][3]*c1.x + Bh[l][4]*c1.y + Bh[l][5]*c1.z + Bh[l][6]*c1.w
                     + Bh[l][7]*c2.x + Bh[l][8]*c2.y + Bh[l][9]*c2.z;
        }
    }
#pragma unroll
    for (int q=0;q<10;++q) {
        const float4 c0 = *(const float4*)&e2[q][0];
        const float4 c1 = *(const float4*)&e2[q][4];
        const float4 c2 = *(const float4*)&e2[q][8];
        float Bq[4];
#pragma unroll
        for (int l=0;l<4;++l) {
            Bq[l] = Rsum[l]*c0.x + Bh[l][0]*c0.y + Bh[l][1]*c0.z + Bh[l][2]*c0.w
                  + Bh[l][3]*c1.x + Bh[l][4]*c1.y + Bh[l][5]*c1.z + Bh[l][6]*c1.w
                  + Bh[l][7]*c2.x + Bh[l][8]*c2.y + Bh[l][9]*c2.z;
        }
        D[q]    = Bk[0][0]*Bq[0]+Bk[0][1]*Bq[1]+Bk[0][2]*Bq[2]+Bk[0][3]*Bq[3];
        D[10+q] = Bk[1][0]*Bq[0]+Bk[1][1]*Bq[1]+Bk[1][2]*Bq[2]+Bk[1][3]*Bq[3];
    }
}

__device__ __forceinline__ float mlp_head_quad(const float* __restrict__ x,
                                          const float* __restrict__ w1, const float* __restrict__ b1,
                                          const float* __restrict__ w2, const float* __restrict__ b2,
                                          const float* __restrict__ w3, int j)
{
    float h1[8];
    {
        float4 ba = *(const float4*)(b1 + 8*j);
        float4 bb = *(const float4*)(b1 + 8*j + 4);
        h1[0]=ba.x; h1[1]=ba.y; h1[2]=ba.z; h1[3]=ba.w;
        h1[4]=bb.x; h1[5]=bb.y; h1[6]=bb.z; h1[7]=bb.w;
    }
#pragma unroll
    for (int d=0; d<20; ++d) {
        float4 w0 = *(const float4*)(w1 + d*32 + 8*j);
        float4 w4 = *(const float4*)(w1 + d*32 + 8*j + 4);
        float xv = x[d];
        h1[0] += xv*w0.x; h1[1] += xv*w0.y; h1[2] += xv*w0.z; h1[3] += xv*w0.w;
        h1[4] += xv*w4.x; h1[5] += xv*w4.y; h1[6] += xv*w4.z; h1[7] += xv*w4.w;
    }
#pragma unroll
    for (int o=0;o<8;++o) h1[o] = fmaxf(h1[o], 0.f);

    float s = 0.f;
#pragma unroll
    for (int half=0; half<2; ++half) {
        float p[16];
#pragma unroll
        for (int q=0;q<16;++q) p[q] = 0.f;
#pragma unroll
        for (int o=0;o<8;++o) {
            const float* row = w2 + (8*j + o)*32 + 16*half;
            float hv = h1[o];
#pragma unroll
            for (int q=0;q<4;++q) {
                float4 w = *(const float4*)(row + 4*q);
                p[4*q+0] += hv*w.x; p[4*q+1] += hv*w.y;
                p[4*q+2] += hv*w.z; p[4*q+3] += hv*w.w;
            }
        }
#pragma unroll
        for (int q=0;q<16;++q) { p[q] += __shfl_xor(p[q],1); p[q] += __shfl_xor(p[q],2); }
#pragma unroll
        for (int q=0;q<4;++q) {
            float4 bq = *(const float4*)(b2 + 16*half + 4*q);
            float4 wq = *(const float4*)(w3 + 16*half + 4*q);
            s += fmaxf(p[4*q+0]+bq.x, 0.f)*wq.x;
            s += fmaxf(p[4*q+1]+bq.y, 0.f)*wq.y;
            s += fmaxf(p[4*q+2]+bq.z, 0.f)*wq.z;
            s += fmaxf(p[4*q+3]+bq.w, 0.f)*wq.w;
        }
    }
    return s;
}

__global__ __launch_bounds__(256) void k_fused(
    const float* __restrict__ Smat, const float* __restrict__ Rraw, const float* __restrict__ Mspec,
    const float* __restrict__ We1, const float* __restrict__ be1,
    const float* __restrict__ We2, const float* __restrict__ be2,
    const float* __restrict__ Wf1, const float* __restrict__ bf1,
    const float* __restrict__ Wf2, const float* __restrict__ bf2,
    const float* __restrict__ Wf3, const float* __restrict__ bf3,
    const float* __restrict__ Wv1, const float* __restrict__ bv1,
    const float* __restrict__ Wv2, const float* __restrict__ bv2,
    const float* __restrict__ Wv3, const float* __restrict__ bv3,
    float* __restrict__ logits, float* __restrict__ pmax,
    float* __restrict__ psum, float* __restrict__ pval, int n)
{
    __shared__ __align__(16) float4 s_e1[10];
    __shared__ __align__(16) float  s_e2[10][12];
    __shared__ __align__(16) float  s_f1[640], s_v1[640];
    __shared__ __align__(16) float  s_f2[1024], s_v2[1024];
    __shared__ __align__(16) float  s_b1[32], s_b2[32], s_f3[32];
    __shared__ __align__(16) float  s_bv1[32], s_bv2[32], s_v3[32];
    __shared__ __align__(16) float  s_a0[64][16];
    __shared__ float red_l[64], red_v[64];

    const int tid = threadIdx.x;
    for (int i=tid;i<640;i+=256){ s_f1[i]=Wf1[i]; s_v1[i]=Wv1[i]; }
    for (int i=tid;i<1024;i+=256){ s_f2[i]=Wf2[i]; s_v2[i]=Wv2[i]; }
    if (tid<32){ s_b1[tid]=bf1[tid]; s_b2[tid]=bf2[tid]; s_f3[tid]=Wf3[tid];
                 s_bv1[tid]=bv1[tid]; s_bv2[tid]=bv2[tid]; s_v3[tid]=Wv3[tid]; }
    if (tid<10){
        s_e1[tid] = make_float4(be1[tid], We1[tid], We1[10+tid], We1[20+tid]);
        s_e2[tid][0] = be2[tid];
        for (int e=0;e<10;++e) s_e2[tid][1+e] = We2[e*10+tid];
        s_e2[tid][11] = 0.f;
    }
    __syncthreads();

    const int j    = tid & 3;
    const int grp  = tid >> 2;
    const int act  = blockIdx.x*64 + grp;
    const bool active = act < n;
    const int actc = active ? act : (n-1);

    const float*  sp = Smat + (size_t)actc*ATOM;
    const float4* rp = (const float4*)Rraw  + (size_t)actc*ATOM;
    const float4* mp = (const float4*)Mspec + (size_t)actc*48;

    float Bh[4][10];
    float Rsum[4] = {0.f,0.f,0.f,0.f};
#pragma unroll
    for (int l=0;l<4;++l)
#pragma unroll
        for (int e=0;e<10;++e) Bh[l][e]=0.f;

#pragma unroll 1
    for (int c=0;c<4;++c) {
        const int a0 = 16*j + 4*c;
        const float4 s4 = *(const float4*)(sp + a0);
        const float4 rv0 = rp[a0+0];
        const float4 rv1 = rp[a0+1];
        const float4 rv2 = rp[a0+2];
        const float4 rv3 = rp[a0+3];
        const float4 mA = mp[12*j+3*c+0];
        const float4 mB = mp[12*j+3*c+1];
        const float4 mC = mp[12*j+3*c+2];

        const float  sv[4]  = {s4.x,s4.y,s4.z,s4.w};
        const float4 rv[4]  = {rv0,rv1,rv2,rv3};
        const float  mk[12] = {mA.x,mA.y,mA.z,mA.w,mB.x,mB.y,mB.z,mB.w,mC.x,mC.y,mC.z,mC.w};

#pragma unroll
        for (int u=0;u<4;++u) {
            const float s   = sv[u];
            const float Rl0 = s*rv[u].x, Rl1 = s*rv[u].y, Rl2 = s*rv[u].z, Rl3 = s*rv[u].w;
            const float sg0 = s*mk[3*u+0], sg1 = s*mk[3*u+1], sg2 = s*mk[3*u+2];
            float h[10];
#pragma unroll
            for (int e=0;e<10;++e) {
                const float4 w = s_e1[e];
                h[e] = fmaxf(0.f, w.x + sg0*w.y + sg1*w.z + sg2*w.w);
            }
            Rsum[0]+=Rl0; Rsum[1]+=Rl1; Rsum[2]+=Rl2; Rsum[3]+=Rl3;
#pragma unroll
            for (int e=0;e<10;++e) {
                const float he = h[e];
                Bh[0][e]+=Rl0*he; Bh[1][e]+=Rl1*he; Bh[2][e]+=Rl2*he; Bh[3][e]+=Rl3*he;
            }
            if (c==0 && u==0 && j==0) {
#pragma unroll
                for (int e=0;e<10;++e) s_a0[grp][e]=h[e];
                s_a0[grp][10]=Rl0; s_a0[grp][11]=Rl1; s_a0[grp][12]=Rl2; s_a0[grp][13]=Rl3;
            }
        }
    }

#pragma unroll
    for (int l=0;l<4;++l) {
        float v=Rsum[l]; v+=__shfl_xor(v,1); v+=__shfl_xor(v,2); Rsum[l]=v;
#pragma unroll
        for (int e=0;e<10;++e) {
            float w=Bh[l][e]; w+=__shfl_xor(w,1); w+=__shfl_xor(w,2); Bh[l][e]=w;
        }
    }

    float Df[20];
    make_D(Bh, Rsum, s_e2, Df);
    {
        const float* a0p = &s_a0[grp][0];
#pragma unroll
        for (int l=0;l<4;++l) {
            const float r0 = a0p[10+l];
            Rsum[l] -= r0;
#pragma unroll
            for (int e=0;e<10;++e) Bh[l][e] -= r0*a0p[e];
        }
    }
    float Dv[20];
    make_D(Bh, Rsum, s_e2, Dv);

    const float logit = mlp_head_quad(Df, s_f1, s_b1, s_f2, s_b2, s_f3, j) + bf3[0];
    const float vout  = mlp_head_quad(Dv, s_v1, s_bv1, s_v2, s_bv2, s_v3, j) + bv3[0];

    if (j==0) {
        red_l[grp] = active ? logit : -INFINITY;
        red_v[grp] = active ? vout  : 0.f;
        if (active) logits[act] = logit;
    }
    __syncthreads();

    if (tid < 64) {
        float m = red_l[tid];
#pragma unroll
        for (int k=1;k<64;k<<=1) m = fmaxf(m, __shfl_xor(m,k));
        float e = expf(red_l[tid] - m);
        float ssum = e, vsum = red_v[tid];
#pragma unroll
        for (int k=1;k<64;k<<=1){ ssum += __shfl_xor(ssum,k); vsum += __shfl_xor(vsum,k); }
        if (tid==0){ pmax[blockIdx.x]=m; psum[blockIdx.x]=ssum; pval[blockIdx.x]=vsum; }
    }
}

// ===========================================================================
// Merge per-block partials -> logZ, value ; apply shift
// ===========================================================================
__global__ __launch_bounds__(256) void k_reduce(const float* __restrict__ pmax,
                                                const float* __restrict__ psum,
                                                const float* __restrict__ pval,
                                                int nb,
                                                float* __restrict__ logZ,
                                                float* __restrict__ value_out)
{
    __shared__ float sm[256];
    const int tid = threadIdx.x;
    float m = -INFINITY;
    for (int i=tid;i<nb;i+=256) m = fmaxf(m, pmax[i]);
    sm[tid]=m; __syncthreads();
    for (int s=128;s>0;s>>=1){ if (tid<s) sm[tid]=fmaxf(sm[tid],sm[tid+s]); __syncthreads(); }
    const float M = sm[0]; __syncthreads();

    float ssum=0.f, vsum=0.f;
    for (int i=tid;i<nb;i+=256){ ssum += psum[i]*expf(pmax[i]-M); vsum += pval[i]; }
    sm[tid]=ssum; __syncthreads();
    for (int s=128;s>0;s>>=1){ if (tid<s) sm[tid]+=sm[tid+s]; __syncthreads(); }
    const float S = sm[0]; __syncthreads();

    sm[tid]=vsum; __syncthreads();
    for (int s=128;s>0;s>>=1){ if (tid<s) sm[tid]+=sm[tid+s]; __syncthreads(); }
    if (tid==0){ *logZ = M + logf(S); *value_out = sm[0]; }
}

__global__ __launch_bounds__(256) void k_apply(const float* __restrict__ logits,
                                               const float* __restrict__ logZ,
                                               float* __restrict__ out, int n)
{
    const int i = blockIdx.x*256 + threadIdx.x;
    if (i < n) out[i] = logits[i] - logZ[0];
}

extern "C" void kernel_launch(void* const* d_in, const int* in_sizes, int n_in,
                              void* d_out, int out_size, void* d_ws, size_t ws_size,
                              hipStream_t stream)
{
    const float* Smat  = (const float*)d_in[0];
    const float* Rraw  = (const float*)d_in[1];
    const float* Mspec = (const float*)d_in[2];
    const float* We1 = (const float*)d_in[3];  const float* be1 = (const float*)d_in[4];
    const float* We2 = (const float*)d_in[5];  const float* be2 = (const float*)d_in[6];
    const float* Wf1 = (const float*)d_in[7];  const float* bf1 = (const float*)d_in[8];
    const float* Wf2 = (const float*)d_in[9];  const float* bf2 = (const float*)d_in[10];
    const float* Wf3 = (const float*)d_in[11]; const float* bf3 = (const float*)d_in[12];
    const float* Wv1 = (const float*)d_in[13]; const float* bv1 = (const float*)d_in[14];
    const float* Wv2 = (const float*)d_in[15]; const float* bv2 = (const float*)d_in[16];
    const float* Wv3 = (const float*)d_in[17]; const float* bv3 = (const float*)d_in[18];

    const int n   = in_sizes[0] / ATOM;
    const int nbE = (n + 63) / 64;            // k_embed / k_fused blocks
    const int nbH = (n + 127) / 128;          // k_head blocks

    float* out = (float*)d_out;               // [n] policy, [1] value
    const size_t need_new = ((size_t)58*n + (size_t)n + 3*(size_t)nbH + 16) * sizeof(float);

    if (ws_size >= need_new) {
        float* ws     = (float*)d_ws;
        float* Vws    = ws;                    // [44*n]
        float* A0ws   = Vws + (size_t)44*n;    // [14*n]
        float* logits = A0ws + (size_t)14*n;   // [n]
        float* pmax   = logits + n;            // [nbH]
        float* psum   = pmax + nbH;            // [nbH]
        float* pval   = psum + nbH;            // [nbH]
        float* logZ   = pval + nbH;            // [1]

        k_embed<<<nbE, 256, 0, stream>>>(Smat, Rraw, Mspec, We1, be1, Vws, A0ws, n);
        k_head<<<nbH, 256, 0, stream>>>(Vws, A0ws, We2, be2,
                                        Wf1, bf1, Wf2, bf2, Wf3, bf3,
                                        Wv1, bv1, Wv2, bv2, Wv3, bv3,
                                        logits, pmax, psum, pval, n);
        k_reduce<<<1, 256, 0, stream>>>(pmax, psum, pval, nbH, logZ, out + n);
        k_apply<<<(n + 255)/256, 256, 0, stream>>>(logits, logZ, out, n);
    } else {
        float* ws     = (float*)d_ws;
        float* logits = ws;                    // [n]
        float* pmax   = ws + n;                // [nbE]
        float* psum   = pmax + nbE;            // [nbE]
        float* pval   = psum + nbE;            // [nbE]
        float* logZ   = pval + nbE;            // [1]

        k_fused<<<nbE, 256, 0, stream>>>(Smat, Rraw, Mspec,
                                         We1, be1, We2, be2,
                                         Wf1, bf1, Wf2, bf2, Wf3, bf3,
                                         Wv1, bv1, Wv2, bv2, Wv3, bv3,
                                         logits, pmax, psum, pval, n);
        k_reduce<<<1, 256, 0, stream>>>(pmax, psum, pval, nbE, logZ, out + n);
        k_apply<<<(n + 255)/256, 256, 0, stream>>>(logits, logZ, out, n);
    }
}

// Round 11
// 87.172 us; speedup vs baseline: 1.4353x; 1.4353x over previous
//
#include <hip/hip_runtime.h>
#include <math.h>

#define ATOM 64

// ===========================================================================
// full per-thread MLP head: x[20] -> 32 -> 32 -> 1 (bias3 added by caller)
// ===========================================================================
__device__ __forceinline__ float full_head(const float (&x)[20],
                                           const float* __restrict__ w1, const float* __restrict__ b1,
                                           const float* __restrict__ w2, const float* __restrict__ b2,
                                           const float* __restrict__ w3)
{
    float h1[32];
#pragma unroll
    for (int q=0;q<8;++q) {
        float4 b = *(const float4*)(b1 + 4*q);
        h1[4*q+0]=b.x; h1[4*q+1]=b.y; h1[4*q+2]=b.z; h1[4*q+3]=b.w;
    }
#pragma unroll
    for (int d=0; d<20; ++d) {
        const float xv = x[d];
        const float* row = w1 + d*32;
#pragma unroll
        for (int q=0;q<8;++q) {
            float4 w = *(const float4*)(row + 4*q);
            h1[4*q+0] += xv*w.x; h1[4*q+1] += xv*w.y;
            h1[4*q+2] += xv*w.z; h1[4*q+3] += xv*w.w;
        }
    }
    float p[32];
#pragma unroll
    for (int q=0;q<8;++q) {
        float4 b = *(const float4*)(b2 + 4*q);
        p[4*q+0]=b.x; p[4*q+1]=b.y; p[4*q+2]=b.z; p[4*q+3]=b.w;
    }
#pragma unroll
    for (int o=0;o<32;++o) {
        const float hv = fmaxf(h1[o], 0.f);
        const float* row = w2 + o*32;
#pragma unroll
        for (int q=0;q<8;++q) {
            float4 w = *(const float4*)(row + 4*q);
            p[4*q+0] += hv*w.x; p[4*q+1] += hv*w.y;
            p[4*q+2] += hv*w.z; p[4*q+3] += hv*w.w;
        }
    }
    float s = 0.f;
#pragma unroll
    for (int q=0;q<8;++q) {
        float4 wq = *(const float4*)(w3 + 4*q);
        s += fmaxf(p[4*q+0], 0.f)*wq.x;
        s += fmaxf(p[4*q+1], 0.f)*wq.y;
        s += fmaxf(p[4*q+2], 0.f)*wq.z;
        s += fmaxf(p[4*q+3], 0.f)*wq.w;
    }
    return s;
}

// ===========================================================================
// R11 Kernel 1: k_embed — R9 structure with 4-DEEP load pipeline.
// 4 lanes/action, interleaved atom ownership (lane j owns atoms 4u+j).
// Four named stage sets (A..D), fully unrolled 16-step schedule:
//   STEP(X,u) then LOAD(X,u+4) — 3-4 batches (6-8 KB/wave) always in flight.
// ===========================================================================
__global__ __launch_bounds__(256) void k_embed(
    const float* __restrict__ Smat, const float* __restrict__ Rraw, const float* __restrict__ Mspec,
    const float* __restrict__ We1, const float* __restrict__ be1,
    float* __restrict__ Vws, float* __restrict__ A0ws, int n)
{
    const int tid = threadIdx.x;
    const int j   = tid & 3;
    const int grp = tid >> 2;
    const int act = blockIdx.x*64 + grp;
    const bool active = act < n;
    const int actc = active ? act : (n-1);

    // e1 weights: uniform loads -> scalar regs
    float e1w0[10], e1w1[10], e1w2[10], e1w3[10];
#pragma unroll
    for (int e=0;e<10;++e){
        e1w0[e]=be1[e]; e1w1[e]=We1[e]; e1w2[e]=We1[10+e]; e1w3[e]=We1[20+e];
    }

    const float4* rp = (const float4*)Rraw + (size_t)actc*ATOM + j;
    const float*  sp = Smat  + (size_t)actc*ATOM + j;
    const float*  mp = Mspec + (size_t)actc*(ATOM*3) + 3*j;

    float Bh[4][10];
    float Rsum[4] = {0.f,0.f,0.f,0.f};
#pragma unroll
    for (int l=0;l<4;++l)
#pragma unroll
        for (int e=0;e<10;++e) Bh[l][e]=0.f;

    float a0h[10], a0r[4];
#pragma unroll
    for (int e=0;e<10;++e) a0h[e]=0.f;
    a0r[0]=a0r[1]=a0r[2]=a0r[3]=0.f;

    // ---- 4-deep software pipeline, fully unrolled (named sets, rule #20) ----
    float4 rA,rB,rC,rD;
    float  sA,sB,sC,sD;
    float  mA0,mA1,mA2, mB0,mB1,mB2, mC0,mC1,mC2, mD0,mD1,mD2;

#define LOADST(R_,S_,M0_,M1_,M2_,u) \
    { R_ = rp[4*(u)]; S_ = sp[4*(u)]; \
      M0_ = mp[12*(u)]; M1_ = mp[12*(u)+1]; M2_ = mp[12*(u)+2]; }

#define STEPST(R_,S_,M0_,M1_,M2_,FIRST) \
    { const float s_ = S_; \
      const float Rl0=s_*R_.x, Rl1=s_*R_.y, Rl2=s_*R_.z, Rl3=s_*R_.w; \
      const float sg0=s_*M0_, sg1=s_*M1_, sg2=s_*M2_; \
      float h[10]; \
      _Pragma("unroll") \
      for (int e=0;e<10;++e) \
          h[e] = fmaxf(0.f, e1w0[e] + sg0*e1w1[e] + sg1*e1w2[e] + sg2*e1w3[e]); \
      Rsum[0]+=Rl0; Rsum[1]+=Rl1; Rsum[2]+=Rl2; Rsum[3]+=Rl3; \
      _Pragma("unroll") \
      for (int e=0;e<10;++e){ \
          const float he=h[e]; \
          Bh[0][e]+=Rl0*he; Bh[1][e]+=Rl1*he; Bh[2][e]+=Rl2*he; Bh[3][e]+=Rl3*he; } \
      if (FIRST && j==0){ \
          _Pragma("unroll") \
          for (int e=0;e<10;++e) a0h[e]=h[e]; \
          a0r[0]=Rl0; a0r[1]=Rl1; a0r[2]=Rl2; a0r[3]=Rl3; } }

    LOADST(rA,sA,mA0,mA1,mA2, 0)
    LOADST(rB,sB,mB0,mB1,mB2, 1)
    LOADST(rC,sC,mC0,mC1,mC2, 2)
    LOADST(rD,sD,mD0,mD1,mD2, 3)

    STEPST(rA,sA,mA0,mA1,mA2, true)   LOADST(rA,sA,mA0,mA1,mA2, 4)
    STEPST(rB,sB,mB0,mB1,mB2, false)  LOADST(rB,sB,mB0,mB1,mB2, 5)
    STEPST(rC,sC,mC0,mC1,mC2, false)  LOADST(rC,sC,mC0,mC1,mC2, 6)
    STEPST(rD,sD,mD0,mD1,mD2, false)  LOADST(rD,sD,mD0,mD1,mD2, 7)
    STEPST(rA,sA,mA0,mA1,mA2, false)  LOADST(rA,sA,mA0,mA1,mA2, 8)
    STEPST(rB,sB,mB0,mB1,mB2, false)  LOADST(rB,sB,mB0,mB1,mB2, 9)
    STEPST(rC,sC,mC0,mC1,mC2, false)  LOADST(rC,sC,mC0,mC1,mC2,10)
    STEPST(rD,sD,mD0,mD1,mD2, false)  LOADST(rD,sD,mD0,mD1,mD2,11)
    STEPST(rA,sA,mA0,mA1,mA2, false)  LOADST(rA,sA,mA0,mA1,mA2,12)
    STEPST(rB,sB,mB0,mB1,mB2, false)  LOADST(rB,sB,mB0,mB1,mB2,13)
    STEPST(rC,sC,mC0,mC1,mC2, false)  LOADST(rC,sC,mC0,mC1,mC2,14)
    STEPST(rD,sD,mD0,mD1,mD2, false)  LOADST(rD,sD,mD0,mD1,mD2,15)
    STEPST(rA,sA,mA0,mA1,mA2, false)
    STEPST(rB,sB,mB0,mB1,mB2, false)
    STEPST(rC,sC,mC0,mC1,mC2, false)
    STEPST(rD,sD,mD0,mD1,mD2, false)

#undef LOADST
#undef STEPST

    // quad butterfly-reduce the 44 accumulators
#pragma unroll
    for (int l=0;l<4;++l) {
        float v=Rsum[l]; v+=__shfl_xor(v,1); v+=__shfl_xor(v,2); Rsum[l]=v;
#pragma unroll
        for (int e=0;e<10;++e) {
            float w=Bh[l][e]; w+=__shfl_xor(w,1); w+=__shfl_xor(w,2); Bh[l][e]=w;
        }
    }

    if (!active) return;
    const size_t N = (size_t)n;
    if (j==0) {
#pragma unroll
        for (int e=0;e<10;++e) Vws[(size_t)e*N + act] = Bh[0][e];
        Vws[(size_t)40*N + act] = Rsum[0];
#pragma unroll
        for (int e=0;e<10;++e) A0ws[(size_t)e*N + act] = a0h[e];
#pragma unroll
        for (int l=0;l<4;++l)  A0ws[(size_t)(10+l)*N + act] = a0r[l];
    } else if (j==1) {
#pragma unroll
        for (int e=0;e<10;++e) Vws[(size_t)(10+e)*N + act] = Bh[1][e];
        Vws[(size_t)41*N + act] = Rsum[1];
    } else if (j==2) {
#pragma unroll
        for (int e=0;e<10;++e) Vws[(size_t)(20+e)*N + act] = Bh[2][e];
        Vws[(size_t)42*N + act] = Rsum[2];
    } else {
#pragma unroll
        for (int e=0;e<10;++e) Vws[(size_t)(30+e)*N + act] = Bh[3][e];
        Vws[(size_t)43*N + act] = Rsum[3];
    }
}

// ===========================================================================
// Kernel 2: k_head — D construction + both MLP heads.
// Block = 256 threads = 128 actions x 2 heads (tid<128 policy, >=128 value).
// ===========================================================================
__global__ __launch_bounds__(256) void k_head(
    const float* __restrict__ Vws, const float* __restrict__ A0ws,
    const float* __restrict__ We2, const float* __restrict__ be2,
    const float* __restrict__ Wf1, const float* __restrict__ bf1,
    const float* __restrict__ Wf2, const float* __restrict__ bf2,
    const float* __restrict__ Wf3, const float* __restrict__ bf3,
    const float* __restrict__ Wv1, const float* __restrict__ bv1,
    const float* __restrict__ Wv2, const float* __restrict__ bv2,
    const float* __restrict__ Wv3, const float* __restrict__ bv3,
    float* __restrict__ logits, float* __restrict__ pmax,
    float* __restrict__ psum, float* __restrict__ pval, int n)
{
    __shared__ __align__(16) float s_e2[10][12];
    __shared__ __align__(16) float s_f1[640], s_v1[640];
    __shared__ __align__(16) float s_f2[1024], s_v2[1024];
    __shared__ __align__(16) float s_b1[32], s_b2[32], s_f3[32];
    __shared__ __align__(16) float s_bv1[32], s_bv2[32], s_v3[32];
    __shared__ float red_l[128], red_v[128];

    const int tid = threadIdx.x;
    for (int i=tid;i<640;i+=256){ s_f1[i]=Wf1[i]; s_v1[i]=Wv1[i]; }
    for (int i=tid;i<1024;i+=256){ s_f2[i]=Wf2[i]; s_v2[i]=Wv2[i]; }
    if (tid<32){ s_b1[tid]=bf1[tid]; s_b2[tid]=bf2[tid]; s_f3[tid]=Wf3[tid];
                 s_bv1[tid]=bv1[tid]; s_bv2[tid]=bv2[tid]; s_v3[tid]=Wv3[tid]; }
    if (tid<10){
        s_e2[tid][0] = be2[tid];
        for (int e=0;e<10;++e) s_e2[tid][1+e] = We2[e*10+tid];
        s_e2[tid][11] = 0.f;
    }
    __syncthreads();

    const int half = tid >> 7;
    const int idx  = tid & 127;
    const int act  = blockIdx.x*128 + idx;
    const bool active = act < n;
    const int actc = active ? act : (n-1);
    const size_t N = (size_t)n;

    float Bh[4][10], Rsum[4];
#pragma unroll
    for (int l=0;l<4;++l)
#pragma unroll
        for (int e=0;e<10;++e) Bh[l][e] = Vws[(size_t)(l*10+e)*N + actc];
#pragma unroll
    for (int l=0;l<4;++l) Rsum[l] = Vws[(size_t)(40+l)*N + actc];

    if (half) {
        float h0[10], r0[4];
#pragma unroll
        for (int e=0;e<10;++e) h0[e] = A0ws[(size_t)e*N + actc];
#pragma unroll
        for (int l=0;l<4;++l)  r0[l] = A0ws[(size_t)(10+l)*N + actc];
#pragma unroll
        for (int l=0;l<4;++l){
            Rsum[l] -= r0[l];
#pragma unroll
            for (int e=0;e<10;++e) Bh[l][e] -= r0[l]*h0[e];
        }
    }

    float Bk0[4], Bk1[4];
#pragma unroll
    for (int k=0;k<2;++k){
        const float4 c0 = *(const float4*)&s_e2[k][0];
        const float4 c1 = *(const float4*)&s_e2[k][4];
        const float4 c2 = *(const float4*)&s_e2[k][8];
#pragma unroll
        for (int l=0;l<4;++l){
            const float v = Rsum[l]*c0.x + Bh[l][0]*c0.y + Bh[l][1]*c0.z + Bh[l][2]*c0.w
                          + Bh[l][3]*c1.x + Bh[l][4]*c1.y + Bh[l][5]*c1.z + Bh[l][6]*c1.w
                          + Bh[l][7]*c2.x + Bh[l][8]*c2.y + Bh[l][9]*c2.z;
            if (k==0) Bk0[l]=v; else Bk1[l]=v;
        }
    }
    float D[20];
#pragma unroll
    for (int q=0;q<10;++q){
        const float4 c0 = *(const float4*)&s_e2[q][0];
        const float4 c1 = *(const float4*)&s_e2[q][4];
        const float4 c2 = *(const float4*)&s_e2[q][8];
        float Bq[4];
#pragma unroll
        for (int l=0;l<4;++l)
            Bq[l] = Rsum[l]*c0.x + Bh[l][0]*c0.y + Bh[l][1]*c0.z + Bh[l][2]*c0.w
                  + Bh[l][3]*c1.x + Bh[l][4]*c1.y + Bh[l][5]*c1.z + Bh[l][6]*c1.w
                  + Bh[l][7]*c2.x + Bh[l][8]*c2.y + Bh[l][9]*c2.z;
        D[q]    = Bk0[0]*Bq[0]+Bk0[1]*Bq[1]+Bk0[2]*Bq[2]+Bk0[3]*Bq[3];
        D[10+q] = Bk1[0]*Bq[0]+Bk1[1]*Bq[1]+Bk1[2]*Bq[2]+Bk1[3]*Bq[3];
    }

    const float* w1 = half ? s_v1  : s_f1;
    const float* b1 = half ? s_bv1 : s_b1;
    const float* w2 = half ? s_v2  : s_f2;
    const float* b2 = half ? s_bv2 : s_b2;
    const float* w3 = half ? s_v3  : s_f3;
    const float  b3 = half ? bv3[0] : bf3[0];
    const float  out = full_head(D, w1, b1, w2, b2, w3) + b3;

    if (half == 0) {
        red_l[idx] = active ? out : -INFINITY;
        if (active) logits[act] = out;
    } else {
        red_v[idx] = active ? out : 0.f;
    }
    __syncthreads();

    if (tid < 64) {
        float m = fmaxf(red_l[tid], red_l[tid+64]);
#pragma unroll
        for (int k=1;k<64;k<<=1) m = fmaxf(m, __shfl_xor(m,k));
        float ssum = expf(red_l[tid]-m) + expf(red_l[tid+64]-m);
        float vsum = red_v[tid] + red_v[tid+64];
#pragma unroll
        for (int k=1;k<64;k<<=1){ ssum += __shfl_xor(ssum,k); vsum += __shfl_xor(vsum,k); }
        if (tid==0){ pmax[blockIdx.x]=m; psum[blockIdx.x]=ssum; pval[blockIdx.x]=vsum; }
    }
}

// ===========================================================================
// Fused fallback (R3 structure, plain 256 bound)
// ===========================================================================
__device__ __forceinline__ void make_D(const float (&Bh)[4][10], const float (&Rsum)[4],
                                       const float (*e2)[12], float (&D)[20])
{
    float Bk[2][4];
#pragma unroll
    for (int k=0;k<2;++k) {
        const float4 c0 = *(const float4*)&e2[k][0];
        const float4 c1 = *(const float4*)&e2[k][4];
        const float4 c2 = *(const float4*)&e2[k][8];
#pragma unroll
        for (int l=0;l<4;++l) {
            Bk[k][l] = Rsum[l]*c0.x + Bh[l][0]*c0.y + Bh[l][1]*c0.z + Bh[l][2]*c0.w
                     + Bh[l][3]*c1.x + Bh[l][4]*c1.y + Bh[l][5]*c1.z + Bh[l][6]*c1.w
                     + Bh[l][7]*c2.x + Bh[l][8]*c2.y + Bh[l][9]*c2.z;
        }
    }
#pragma unroll
    for (int q=0;q<10;++q) {
        const float4 c0 = *(const float4*)&e2[q][0];
        const float4 c1 = *(const float4*)&e2[q][4];
        const float4 c2 = *(const float4*)&e2[q][8];
        float Bq[4];
#pragma unroll
        for (int l=0;l<4;++l) {
            Bq[l] = Rsum[l]*c0.x + Bh[l][0]*c0.y + Bh[l][1]*c0.z + Bh[l][2]*c0.w
                  + Bh[l][3]*c1.x + Bh[l][4]*c1.y + Bh[l][5]*c1.z + Bh[l][6]*c1.w
                  + Bh[l][7]*c2.x + Bh[l][8]*c2.y + Bh[l][9]*c2.z;
        }
        D[q]    = Bk[0][0]*Bq[0]+Bk[0][1]*Bq[1]+Bk[0][2]*Bq[2]+Bk[0][3]*Bq[3];
        D[10+q] = Bk[1][0]*Bq[0]+Bk[1][1]*Bq[1]+Bk[1][2]*Bq[2]+Bk[1][3]*Bq[3];
    }
}

__device__ __forceinline__ float mlp_head_quad(const float* __restrict__ x,
                                          const float* __restrict__ w1, const float* __restrict__ b1,
                                          const float* __restrict__ w2, const float* __restrict__ b2,
                                          const float* __restrict__ w3, int j)
{
    float h1[8];
    {
        float4 ba = *(const float4*)(b1 + 8*j);
        float4 bb = *(const float4*)(b1 + 8*j + 4);
        h1[0]=ba.x; h1[1]=ba.y; h1[2]=ba.z; h1[3]=ba.w;
        h1[4]=bb.x; h1[5]=bb.y; h1[6]=bb.z; h1[7]=bb.w;
    }
#pragma unroll
    for (int d=0; d<20; ++d) {
        float4 w0 = *(const float4*)(w1 + d*32 + 8*j);
        float4 w4 = *(const float4*)(w1 + d*32 + 8*j + 4);
        float xv = x[d];
        h1[0] += xv*w0.x; h1[1] += xv*w0.y; h1[2] += xv*w0.z; h1[3] += xv*w0.w;
        h1[4] += xv*w4.x; h1[5] += xv*w4.y; h1[6] += xv*w4.z; h1[7] += xv*w4.w;
    }
#pragma unroll
    for (int o=0;o<8;++o) h1[o] = fmaxf(h1[o], 0.f);

    float s = 0.f;
#pragma unroll
    for (int half=0; half<2; ++half) {
        float p[16];
#pragma unroll
        for (int q=0;q<16;++q) p[q] = 0.f;
#pragma unroll
        for (int o=0;o<8;++o) {
            const float* row = w2 + (8*j + o)*32 + 16*half;
            float hv = h1[o];
#pragma unroll
            for (int q=0;q<4;++q) {
                float4 w = *(const float4*)(row + 4*q);
                p[4*q+0] += hv*w.x; p[4*q+1] += hv*w.y;
                p[4*q+2] += hv*w.z; p[4*q+3] += hv*w.w;
            }
        }
#pragma unroll
        for (int q=0;q<16;++q) { p[q] += __shfl_xor(p[q],1); p[q] += __shfl_xor(p[q],2); }
#pragma unroll
        for (int q=0;q<4;++q) {
            float4 bq = *(const float4*)(b2 + 16*half + 4*q);
            float4 wq = *(const float4*)(w3 + 16*half + 4*q);
            s += fmaxf(p[4*q+0]+bq.x, 0.f)*wq.x;
            s += fmaxf(p[4*q+1]+bq.y, 0.f)*wq.y;
            s += fmaxf(p[4*q+2]+bq.z, 0.f)*wq.z;
            s += fmaxf(p[4*q+3]+bq.w, 0.f)*wq.w;
        }
    }
    return s;
}

__global__ __launch_bounds__(256) void k_fused(
    const float* __restrict__ Smat, const float* __restrict__ Rraw, const float* __restrict__ Mspec,
    const float* __restrict__ We1, const float* __restrict__ be1,
    const float* __restrict__ We2, const float* __restrict__ be2,
    const float* __restrict__ Wf1, const float* __restrict__ bf1,
    const float* __restrict__ Wf2, const float* __restrict__ bf2,
    const float* __restrict__ Wf3, const float* __restrict__ bf3,
    const float* __restrict__ Wv1, const float* __restrict__ bv1,
    const float* __restrict__ Wv2, const float* __restrict__ bv2,
    const float* __restrict__ Wv3, const float* __restrict__ bv3,
    float* __restrict__ logits, float* __restrict__ pmax,
    float* __restrict__ psum, float* __restrict__ pval, int n)
{
    __shared__ __align__(16) float4 s_e1[10];
    __shared__ __align__(16) float  s_e2[10][12];
    __shared__ __align__(16) float  s_f1[640], s_v1[640];
    __shared__ __align__(16) float  s_f2[1024], s_v2[1024];
    __shared__ __align__(16) float  s_b1[32], s_b2[32], s_f3[32];
    __shared__ __align__(16) float  s_bv1[32], s_bv2[32], s_v3[32];
    __shared__ __align__(16) float  s_a0[64][16];
    __shared__ float red_l[64], red_v[64];

    const int tid = threadIdx.x;
    for (int i=tid;i<640;i+=256){ s_f1[i]=Wf1[i]; s_v1[i]=Wv1[i]; }
    for (int i=tid;i<1024;i+=256){ s_f2[i]=Wf2[i]; s_v2[i]=Wv2[i]; }
    if (tid<32){ s_b1[tid]=bf1[tid]; s_b2[tid]=bf2[tid]; s_f3[tid]=Wf3[tid];
                 s_bv1[tid]=bv1[tid]; s_bv2[tid]=bv2[tid]; s_v3[tid]=Wv3[tid]; }
    if (tid<10){
        s_e1[tid] = make_float4(be1[tid], We1[tid], We1[10+tid], We1[20+tid]);
        s_e2[tid][0] = be2[tid];
        for (int e=0;e<10;++e) s_e2[tid][1+e] = We2[e*10+tid];
        s_e2[tid][11] = 0.f;
    }
    __syncthreads();

    const int j    = tid & 3;
    const int grp  = tid >> 2;
    const int act  = blockIdx.x*64 + grp;
    const bool active = act < n;
    const int actc = active ? act : (n-1);

    const float*  sp = Smat + (size_t)actc*ATOM;
    const float4* rp = (const float4*)Rraw  + (size_t)actc*ATOM;
    const float4* mp = (const float4*)Mspec + (size_t)actc*48;

    float Bh[4][10];
    float Rsum[4] = {0.f,0.f,0.f,0.f};
#pragma unroll
    for (int l=0;l<4;++l)
#pragma unroll
        for (int e=0;e<10;++e) Bh[l][e]=0.f;

#pragma unroll 1
    for (int c=0;c<4;++c) {
        const int a0 = 16*j + 4*c;
        const float4 s4 = *(const float4*)(sp + a0);
        const float4 rv0 = rp[a0+0];
        const float4 rv1 = rp[a0+1];
        const float4 rv2 = rp[a0+2];
        const float4 rv3 = rp[a0+3];
        const float4 mA = mp[12*j+3*c+0];
        const float4 mB = mp[12*j+3*c+1];
        const float4 mC = mp[12*j+3*c+2];

        const float  sv[4]  = {s4.x,s4.y,s4.z,s4.w};
        const float4 rv[4]  = {rv0,rv1,rv2,rv3};
        const float  mk[12] = {mA.x,mA.y,mA.z,mA.w,mB.x,mB.y,mB.z,mB.w,mC.x,mC.y,mC.z,mC.w};

#pragma unroll
        for (int u=0;u<4;++u) {
            const float s   = sv[u];
            const float Rl0 = s*rv[u].x, Rl1 = s*rv[u].y, Rl2 = s*rv[u].z, Rl3 = s*rv[u].w;
            const float sg0 = s*mk[3*u+0], sg1 = s*mk[3*u+1], sg2 = s*mk[3*u+2];
            float h[10];
#pragma unroll
            for (int e=0;e<10;++e) {
                const float4 w = s_e1[e];
                h[e] = fmaxf(0.f, w.x + sg0*w.y + sg1*w.z + sg2*w.w);
            }
            Rsum[0]+=Rl0; Rsum[1]+=Rl1; Rsum[2]+=Rl2; Rsum[3]+=Rl3;
#pragma unroll
            for (int e=0;e<10;++e) {
                const float he = h[e];
                Bh[0][e]+=Rl0*he; Bh[1][e]+=Rl1*he; Bh[2][e]+=Rl2*he; Bh[3][e]+=Rl3*he;
            }
            if (c==0 && u==0 && j==0) {
#pragma unroll
                for (int e=0;e<10;++e) s_a0[grp][e]=h[e];
                s_a0[grp][10]=Rl0; s_a0[grp][11]=Rl1; s_a0[grp][12]=Rl2; s_a0[grp][13]=Rl3;
            }
        }
    }

#pragma unroll
    for (int l=0;l<4;++l) {
        float v=Rsum[l]; v+=__shfl_xor(v,1); v+=__shfl_xor(v,2); Rsum[l]=v;
#pragma unroll
        for (int e=0;e<10;++e) {
            float w=Bh[l][e]; w+=__shfl_xor(w,1); w+=__shfl_xor(w,2); Bh[l][e]=w;
        }
    }

    float Df[20];
    make_D(Bh, Rsum, s_e2, Df);
    {
        const float* a0p = &s_a0[grp][0];
#pragma unroll
        for (int l=0;l<4;++l) {
            const float r0 = a0p[10+l];
            Rsum[l] -= r0;
#pragma unroll
            for (int e=0;e<10;++e) Bh[l][e] -= r0*a0p[e];
        }
    }
    float Dv[20];
    make_D(Bh, Rsum, s_e2, Dv);

    const float logit = mlp_head_quad(Df, s_f1, s_b1, s_f2, s_b2, s_f3, j) + bf3[0];
    const float vout  = mlp_head_quad(Dv, s_v1, s_bv1, s_v2, s_bv2, s_v3, j) + bv3[0];

    if (j==0) {
        red_l[grp] = active ? logit : -INFINITY;
        red_v[grp] = active ? vout  : 0.f;
        if (active) logits[act] = logit;
    }
    __syncthreads();

    if (tid < 64) {
        float m = red_l[tid];
#pragma unroll
        for (int k=1;k<64;k<<=1) m = fmaxf(m, __shfl_xor(m,k));
        float e = expf(red_l[tid] - m);
        float ssum = e, vsum = red_v[tid];
#pragma unroll
        for (int k=1;k<64;k<<=1){ ssum += __shfl_xor(ssum,k); vsum += __shfl_xor(vsum,k); }
        if (tid==0){ pmax[blockIdx.x]=m; psum[blockIdx.x]=ssum; pval[blockIdx.x]=vsum; }
    }
}

// ===========================================================================
// Merge per-block partials -> logZ, value ; apply shift
// ===========================================================================
__global__ __launch_bounds__(256) void k_reduce(const float* __restrict__ pmax,
                                                const float* __restrict__ psum,
                                                const float* __restrict__ pval,
                                                int nb,
                                                float* __restrict__ logZ,
                                                float* __restrict__ value_out)
{
    __shared__ float sm[256];
    const int tid = threadIdx.x;
    float m = -INFINITY;
    for (int i=tid;i<nb;i+=256) m = fmaxf(m, pmax[i]);
    sm[tid]=m; __syncthreads();
    for (int s=128;s>0;s>>=1){ if (tid<s) sm[tid]=fmaxf(sm[tid],sm[tid+s]); __syncthreads(); }
    const float M = sm[0]; __syncthreads();

    float ssum=0.f, vsum=0.f;
    for (int i=tid;i<nb;i+=256){ ssum += psum[i]*expf(pmax[i]-M); vsum += pval[i]; }
    sm[tid]=ssum; __syncthreads();
    for (int s=128;s>0;s>>=1){ if (tid<s) sm[tid]+=sm[tid+s]; __syncthreads(); }
    const float S = sm[0]; __syncthreads();

    sm[tid]=vsum; __syncthreads();
    for (int s=128;s>0;s>>=1){ if (tid<s) sm[tid]+=sm[tid+s]; __syncthreads(); }
    if (tid==0){ *logZ = M + logf(S); *value_out = sm[0]; }
}

__global__ __launch_bounds__(256) void k_apply(const float* __restrict__ logits,
                                               const float* __restrict__ logZ,
                                               float* __restrict__ out, int n)
{
    const int i = blockIdx.x*256 + threadIdx.x;
    if (i < n) out[i] = logits[i] - logZ[0];
}

extern "C" void kernel_launch(void* const* d_in, const int* in_sizes, int n_in,
                              void* d_out, int out_size, void* d_ws, size_t ws_size,
                              hipStream_t stream)
{
    const float* Smat  = (const float*)d_in[0];
    const float* Rraw  = (const float*)d_in[1];
    const float* Mspec = (const float*)d_in[2];
    const float* We1 = (const float*)d_in[3];  const float* be1 = (const float*)d_in[4];
    const float* We2 = (const float*)d_in[5];  const float* be2 = (const float*)d_in[6];
    const float* Wf1 = (const float*)d_in[7];  const float* bf1 = (const float*)d_in[8];
    const float* Wf2 = (const float*)d_in[9];  const float* bf2 = (const float*)d_in[10];
    const float* Wf3 = (const float*)d_in[11]; const float* bf3 = (const float*)d_in[12];
    const float* Wv1 = (const float*)d_in[13]; const float* bv1 = (const float*)d_in[14];
    const float* Wv2 = (const float*)d_in[15]; const float* bv2 = (const float*)d_in[16];
    const float* Wv3 = (const float*)d_in[17]; const float* bv3 = (const float*)d_in[18];

    const int n   = in_sizes[0] / ATOM;
    const int nbE = (n + 63) / 64;            // k_embed / k_fused blocks
    const int nbH = (n + 127) / 128;          // k_head blocks

    float* out = (float*)d_out;               // [n] policy, [1] value
    const size_t need_new = ((size_t)58*n + (size_t)n + 3*(size_t)nbH + 16) * sizeof(float);

    if (ws_size >= need_new) {
        float* ws     = (float*)d_ws;
        float* Vws    = ws;                    // [44*n]
        float* A0ws   = Vws + (size_t)44*n;    // [14*n]
        float* logits = A0ws + (size_t)14*n;   // [n]
        float* pmax   = logits + n;            // [nbH]
        float* psum   = pmax + nbH;            // [nbH]
        float* pval   = psum + nbH;            // [nbH]
        float* logZ   = pval + nbH;            // [1]

        k_embed<<<nbE, 256, 0, stream>>>(Smat, Rraw, Mspec, We1, be1, Vws, A0ws, n);
        k_head<<<nbH, 256, 0, stream>>>(Vws, A0ws, We2, be2,
                                        Wf1, bf1, Wf2, bf2, Wf3, bf3,
                                        Wv1, bv1, Wv2, bv2, Wv3, bv3,
                                        logits, pmax, psum, pval, n);
        k_reduce<<<1, 256, 0, stream>>>(pmax, psum, pval, nbH, logZ, out + n);
        k_apply<<<(n + 255)/256, 256, 0, stream>>>(logits, logZ, out, n);
    } else {
        float* ws     = (float*)d_ws;
        float* logits = ws;                    // [n]
        float* pmax   = ws + n;                // [nbE]
        float* psum   = pmax + nbE;            // [nbE]
        float* pval   = psum + nbE;            // [nbE]
        float* logZ   = pval + nbE;            // [1]

        k_fused<<<nbE, 256, 0, stream>>>(Smat, Rraw, Mspec,
                                         We1, be1, We2, be2,
                                         Wf1, bf1, Wf2, bf2, Wf3, bf3,
                                         Wv1, bv1, Wv2, bv2, Wv3, bv3,
                                         logits, pmax, psum, pval, n);
        k_reduce<<<1, 256, 0, stream>>>(pmax, psum, pval, nbE, logZ, out + n);
        k_apply<<<(n + 255)/256, 256, 0, stream>>>(logits, logZ, out, n);
    }
}

// Round 12
// 83.149 us; speedup vs baseline: 1.5048x; 1.0484x over previous
//
#include <hip/hip_runtime.h>
#include <math.h>

#define ATOM 64

// ===========================================================================
// full per-thread MLP head: x[20] -> 32 -> 32 -> 1 (bias3 added by caller)
// ===========================================================================
__device__ __forceinline__ float full_head(const float (&x)[20],
                                           const float* __restrict__ w1, const float* __restrict__ b1,
                                           const float* __restrict__ w2, const float* __restrict__ b2,
                                           const float* __restrict__ w3)
{
    float h1[32];
#pragma unroll
    for (int q=0;q<8;++q) {
        float4 b = *(const float4*)(b1 + 4*q);
        h1[4*q+0]=b.x; h1[4*q+1]=b.y; h1[4*q+2]=b.z; h1[4*q+3]=b.w;
    }
#pragma unroll
    for (int d=0; d<20; ++d) {
        const float xv = x[d];
        const float* row = w1 + d*32;
#pragma unroll
        for (int q=0;q<8;++q) {
            float4 w = *(const float4*)(row + 4*q);
            h1[4*q+0] += xv*w.x; h1[4*q+1] += xv*w.y;
            h1[4*q+2] += xv*w.z; h1[4*q+3] += xv*w.w;
        }
    }
    float p[32];
#pragma unroll
    for (int q=0;q<8;++q) {
        float4 b = *(const float4*)(b2 + 4*q);
        p[4*q+0]=b.x; p[4*q+1]=b.y; p[4*q+2]=b.z; p[4*q+3]=b.w;
    }
#pragma unroll
    for (int o=0;o<32;++o) {
        const float hv = fmaxf(h1[o], 0.f);
        const float* row = w2 + o*32;
#pragma unroll
        for (int q=0;q<8;++q) {
            float4 w = *(const float4*)(row + 4*q);
            p[4*q+0] += hv*w.x; p[4*q+1] += hv*w.y;
            p[4*q+2] += hv*w.z; p[4*q+3] += hv*w.w;
        }
    }
    float s = 0.f;
#pragma unroll
    for (int q=0;q<8;++q) {
        float4 wq = *(const float4*)(w3 + 4*q);
        s += fmaxf(p[4*q+0], 0.f)*wq.x;
        s += fmaxf(p[4*q+1], 0.f)*wq.y;
        s += fmaxf(p[4*q+2], 0.f)*wq.z;
        s += fmaxf(p[4*q+3], 0.f)*wq.w;
    }
    return s;
}

// ===========================================================================
// R12 Kernel 1: k_embed — 8 lanes/action (atoms 8u+j), 32 actions/block.
// DOUBLE the wave count of R9/R11 (12500 waves, ~12/SIMD demanded) to hide
// the ~600-900cy L3/HBM latency chain by TLP. 2-deep named prefetch.
// Output layout unchanged (Vws rows 0..43, A0ws rows 0..13, transposed [row][n]).
// ===========================================================================
__global__ __launch_bounds__(256) void k_embed(
    const float* __restrict__ Smat, const float* __restrict__ Rraw, const float* __restrict__ Mspec,
    const float* __restrict__ We1, const float* __restrict__ be1,
    float* __restrict__ Vws, float* __restrict__ A0ws, int n)
{
    const int tid = threadIdx.x;
    const int j   = tid & 7;              // lane within 8-lane action group
    const int grp = tid >> 3;             // action within block (0..31)
    const int act = blockIdx.x*32 + grp;
    const bool active = act < n;
    const int actc = active ? act : (n-1);

    // e1 weights: uniform loads -> scalar regs
    float e1w0[10], e1w1[10], e1w2[10], e1w3[10];
#pragma unroll
    for (int e=0;e<10;++e){
        e1w0[e]=be1[e]; e1w1[e]=We1[e]; e1w2[e]=We1[10+e]; e1w3[e]=We1[20+e];
    }

    const float4* rp = (const float4*)Rraw + (size_t)actc*ATOM + j;
    const float*  sp = Smat  + (size_t)actc*ATOM + j;
    const float*  mp = Mspec + (size_t)actc*(ATOM*3) + 3*j;

    float Bh[4][10];
    float Rsum[4] = {0.f,0.f,0.f,0.f};
#pragma unroll
    for (int l=0;l<4;++l)
#pragma unroll
        for (int e=0;e<10;++e) Bh[l][e]=0.f;

    float a0h[10], a0r[4];
#pragma unroll
    for (int e=0;e<10;++e) a0h[e]=0.f;
    a0r[0]=a0r[1]=a0r[2]=a0r[3]=0.f;

    // ---- 2-deep software pipeline over 8 atom-steps (named sets, rule #20) ----
    float4 rA,rB;
    float  sA,sB;
    float  mA0,mA1,mA2, mB0,mB1,mB2;

#define LOADST(R_,S_,M0_,M1_,M2_,u) \
    { R_ = rp[8*(u)]; S_ = sp[8*(u)]; \
      M0_ = mp[24*(u)]; M1_ = mp[24*(u)+1]; M2_ = mp[24*(u)+2]; }

#define STEPST(R_,S_,M0_,M1_,M2_,FIRST) \
    { const float s_ = S_; \
      const float Rl0=s_*R_.x, Rl1=s_*R_.y, Rl2=s_*R_.z, Rl3=s_*R_.w; \
      const float sg0=s_*M0_, sg1=s_*M1_, sg2=s_*M2_; \
      float h[10]; \
      _Pragma("unroll") \
      for (int e=0;e<10;++e) \
          h[e] = fmaxf(0.f, e1w0[e] + sg0*e1w1[e] + sg1*e1w2[e] + sg2*e1w3[e]); \
      Rsum[0]+=Rl0; Rsum[1]+=Rl1; Rsum[2]+=Rl2; Rsum[3]+=Rl3; \
      _Pragma("unroll") \
      for (int e=0;e<10;++e){ \
          const float he=h[e]; \
          Bh[0][e]+=Rl0*he; Bh[1][e]+=Rl1*he; Bh[2][e]+=Rl2*he; Bh[3][e]+=Rl3*he; } \
      if (FIRST && j==0){ \
          _Pragma("unroll") \
          for (int e=0;e<10;++e) a0h[e]=h[e]; \
          a0r[0]=Rl0; a0r[1]=Rl1; a0r[2]=Rl2; a0r[3]=Rl3; } }

    LOADST(rA,sA,mA0,mA1,mA2, 0)
    LOADST(rB,sB,mB0,mB1,mB2, 1)

    STEPST(rA,sA,mA0,mA1,mA2, true)   LOADST(rA,sA,mA0,mA1,mA2, 2)
    STEPST(rB,sB,mB0,mB1,mB2, false)  LOADST(rB,sB,mB0,mB1,mB2, 3)
    STEPST(rA,sA,mA0,mA1,mA2, false)  LOADST(rA,sA,mA0,mA1,mA2, 4)
    STEPST(rB,sB,mB0,mB1,mB2, false)  LOADST(rB,sB,mB0,mB1,mB2, 5)
    STEPST(rA,sA,mA0,mA1,mA2, false)  LOADST(rA,sA,mA0,mA1,mA2, 6)
    STEPST(rB,sB,mB0,mB1,mB2, false)  LOADST(rB,sB,mB0,mB1,mB2, 7)
    STEPST(rA,sA,mA0,mA1,mA2, false)
    STEPST(rB,sB,mB0,mB1,mB2, false)

#undef LOADST
#undef STEPST

    // 8-lane butterfly-reduce the 44 accumulators (xor 1,2,4)
#pragma unroll
    for (int l=0;l<4;++l) {
        float v=Rsum[l];
        v+=__shfl_xor(v,1); v+=__shfl_xor(v,2); v+=__shfl_xor(v,4);
        Rsum[l]=v;
#pragma unroll
        for (int e=0;e<10;++e) {
            float w=Bh[l][e];
            w+=__shfl_xor(w,1); w+=__shfl_xor(w,2); w+=__shfl_xor(w,4);
            Bh[l][e]=w;
        }
    }

    if (!active) return;
    const size_t N = (size_t)n;
    // lanes 0..3 store Bh[j][*] + Rsum[j]; lane 0 additionally stores atom-0 state
    if (j==0) {
#pragma unroll
        for (int e=0;e<10;++e) Vws[(size_t)e*N + act] = Bh[0][e];
        Vws[(size_t)40*N + act] = Rsum[0];
#pragma unroll
        for (int e=0;e<10;++e) A0ws[(size_t)e*N + act] = a0h[e];
#pragma unroll
        for (int l=0;l<4;++l)  A0ws[(size_t)(10+l)*N + act] = a0r[l];
    } else if (j==1) {
#pragma unroll
        for (int e=0;e<10;++e) Vws[(size_t)(10+e)*N + act] = Bh[1][e];
        Vws[(size_t)41*N + act] = Rsum[1];
    } else if (j==2) {
#pragma unroll
        for (int e=0;e<10;++e) Vws[(size_t)(20+e)*N + act] = Bh[2][e];
        Vws[(size_t)42*N + act] = Rsum[2];
    } else if (j==3) {
#pragma unroll
        for (int e=0;e<10;++e) Vws[(size_t)(30+e)*N + act] = Bh[3][e];
        Vws[(size_t)43*N + act] = Rsum[3];
    }
}

// ===========================================================================
// Kernel 2: k_head — D construction + both MLP heads.
// Block = 256 threads = 128 actions x 2 heads (tid<128 policy, >=128 value).
// ===========================================================================
__global__ __launch_bounds__(256) void k_head(
    const float* __restrict__ Vws, const float* __restrict__ A0ws,
    const float* __restrict__ We2, const float* __restrict__ be2,
    const float* __restrict__ Wf1, const float* __restrict__ bf1,
    const float* __restrict__ Wf2, const float* __restrict__ bf2,
    const float* __restrict__ Wf3, const float* __restrict__ bf3,
    const float* __restrict__ Wv1, const float* __restrict__ bv1,
    const float* __restrict__ Wv2, const float* __restrict__ bv2,
    const float* __restrict__ Wv3, const float* __restrict__ bv3,
    float* __restrict__ logits, float* __restrict__ pmax,
    float* __restrict__ psum, float* __restrict__ pval, int n)
{
    __shared__ __align__(16) float s_e2[10][12];
    __shared__ __align__(16) float s_f1[640], s_v1[640];
    __shared__ __align__(16) float s_f2[1024], s_v2[1024];
    __shared__ __align__(16) float s_b1[32], s_b2[32], s_f3[32];
    __shared__ __align__(16) float s_bv1[32], s_bv2[32], s_v3[32];
    __shared__ float red_l[128], red_v[128];

    const int tid = threadIdx.x;
    for (int i=tid;i<640;i+=256){ s_f1[i]=Wf1[i]; s_v1[i]=Wv1[i]; }
    for (int i=tid;i<1024;i+=256){ s_f2[i]=Wf2[i]; s_v2[i]=Wv2[i]; }
    if (tid<32){ s_b1[tid]=bf1[tid]; s_b2[tid]=bf2[tid]; s_f3[tid]=Wf3[tid];
                 s_bv1[tid]=bv1[tid]; s_bv2[tid]=bv2[tid]; s_v3[tid]=Wv3[tid]; }
    if (tid<10){
        s_e2[tid][0] = be2[tid];
        for (int e=0;e<10;++e) s_e2[tid][1+e] = We2[e*10+tid];
        s_e2[tid][11] = 0.f;
    }
    __syncthreads();

    const int half = tid >> 7;
    const int idx  = tid & 127;
    const int act  = blockIdx.x*128 + idx;
    const bool active = act < n;
    const int actc = active ? act : (n-1);
    const size_t N = (size_t)n;

    float Bh[4][10], Rsum[4];
#pragma unroll
    for (int l=0;l<4;++l)
#pragma unroll
        for (int e=0;e<10;++e) Bh[l][e] = Vws[(size_t)(l*10+e)*N + actc];
#pragma unroll
    for (int l=0;l<4;++l) Rsum[l] = Vws[(size_t)(40+l)*N + actc];

    if (half) {
        float h0[10], r0[4];
#pragma unroll
        for (int e=0;e<10;++e) h0[e] = A0ws[(size_t)e*N + actc];
#pragma unroll
        for (int l=0;l<4;++l)  r0[l] = A0ws[(size_t)(10+l)*N + actc];
#pragma unroll
        for (int l=0;l<4;++l){
            Rsum[l] -= r0[l];
#pragma unroll
            for (int e=0;e<10;++e) Bh[l][e] -= r0[l]*h0[e];
        }
    }

    float Bk0[4], Bk1[4];
#pragma unroll
    for (int k=0;k<2;++k){
        const float4 c0 = *(const float4*)&s_e2[k][0];
        const float4 c1 = *(const float4*)&s_e2[k][4];
        const float4 c2 = *(const float4*)&s_e2[k][8];
#pragma unroll
        for (int l=0;l<4;++l){
            const float v = Rsum[l]*c0.x + Bh[l][0]*c0.y + Bh[l][1]*c0.z + Bh[l][2]*c0.w
                          + Bh[l][3]*c1.x + Bh[l][4]*c1.y + Bh[l][5]*c1.z + Bh[l][6]*c1.w
                          + Bh[l][7]*c2.x + Bh[l][8]*c2.y + Bh[l][9]*c2.z;
            if (k==0) Bk0[l]=v; else Bk1[l]=v;
        }
    }
    float D[20];
#pragma unroll
    for (int q=0;q<10;++q){
        const float4 c0 = *(const float4*)&s_e2[q][0];
        const float4 c1 = *(const float4*)&s_e2[q][4];
        const float4 c2 = *(const float4*)&s_e2[q][8];
        float Bq[4];
#pragma unroll
        for (int l=0;l<4;++l)
            Bq[l] = Rsum[l]*c0.x + Bh[l][0]*c0.y + Bh[l][1]*c0.z + Bh[l][2]*c0.w
                  + Bh[l][3]*c1.x + Bh[l][4]*c1.y + Bh[l][5]*c1.z + Bh[l][6]*c1.w
                  + Bh[l][7]*c2.x + Bh[l][8]*c2.y + Bh[l][9]*c2.z;
        D[q]    = Bk0[0]*Bq[0]+Bk0[1]*Bq[1]+Bk0[2]*Bq[2]+Bk0[3]*Bq[3];
        D[10+q] = Bk1[0]*Bq[0]+Bk1[1]*Bq[1]+Bk1[2]*Bq[2]+Bk1[3]*Bq[3];
    }

    const float* w1 = half ? s_v1  : s_f1;
    const float* b1 = half ? s_bv1 : s_b1;
    const float* w2 = half ? s_v2  : s_f2;
    const float* b2 = half ? s_bv2 : s_b2;
    const float* w3 = half ? s_v3  : s_f3;
    const float  b3 = half ? bv3[0] : bf3[0];
    const float  out = full_head(D, w1, b1, w2, b2, w3) + b3;

    if (half == 0) {
        red_l[idx] = active ? out : -INFINITY;
        if (active) logits[act] = out;
    } else {
        red_v[idx] = active ? out : 0.f;
    }
    __syncthreads();

    if (tid < 64) {
        float m = fmaxf(red_l[tid], red_l[tid+64]);
#pragma unroll
        for (int k=1;k<64;k<<=1) m = fmaxf(m, __shfl_xor(m,k));
        float ssum = expf(red_l[tid]-m) + expf(red_l[tid+64]-m);
        float vsum = red_v[tid] + red_v[tid+64];
#pragma unroll
        for (int k=1;k<64;k<<=1){ ssum += __shfl_xor(ssum,k); vsum += __shfl_xor(vsum,k); }
        if (tid==0){ pmax[blockIdx.x]=m; psum[blockIdx.x]=ssum; pval[blockIdx.x]=vsum; }
    }
}

// ===========================================================================
// Fused fallback (R3 structure, plain 256 bound)
// ===========================================================================
__device__ __forceinline__ void make_D(const float (&Bh)[4][10], const float (&Rsum)[4],
                                       const float (*e2)[12], float (&D)[20])
{
    float Bk[2][4];
#pragma unroll
    for (int k=0;k<2;++k) {
        const float4 c0 = *(const float4*)&e2[k][0];
        const float4 c1 = *(const float4*)&e2[k][4];
        const float4 c2 = *(const float4*)&e2[k][8];
#pragma unroll
        for (int l=0;l<4;++l) {
            Bk[k][l] = Rsum[l]*c0.x + Bh[l][0]*c0.y + Bh[l][1]*c0.z + Bh[l][2]*c0.w
                     + Bh[l][3]*c1.x + Bh[l][4]*c1.y + Bh[l][5]*c1.z + Bh[l][6]*c1.w
                     + Bh[l][7]*c2.x + Bh[l][8]*c2.y + Bh[l][9]*c2.z;
        }
    }
#pragma unroll
    for (int q=0;q<10;++q) {
        const float4 c0 = *(const float4*)&e2[q][0];
        const float4 c1 = *(const float4*)&e2[q][4];
        const float4 c2 = *(const float4*)&e2[q][8];
        float Bq[4];
#pragma unroll
        for (int l=0;l<4;++l) {
            Bq[l] = Rsum[l]*c0.x + Bh[l][0]*c0.y + Bh[l][1]*c0.z + Bh[l][2]*c0.w
                  + Bh[l][3]*c1.x + Bh[l][4]*c1.y + Bh[l][5]*c1.z + Bh[l][6]*c1.w
                  + Bh[l][7]*c2.x + Bh[l][8]*c2.y + Bh[l][9]*c2.z;
        }
        D[q]    = Bk[0][0]*Bq[0]+Bk[0][1]*Bq[1]+Bk[0][2]*Bq[2]+Bk[0][3]*Bq[3];
        D[10+q] = Bk[1][0]*Bq[0]+Bk[1][1]*Bq[1]+Bk[1][2]*Bq[2]+Bk[1][3]*Bq[3];
    }
}

__device__ __forceinline__ float mlp_head_quad(const float* __restrict__ x,
                                          const float* __restrict__ w1, const float* __restrict__ b1,
                                          const float* __restrict__ w2, const float* __restrict__ b2,
                                          const float* __restrict__ w3, int j)
{
    float h1[8];
    {
        float4 ba = *(const float4*)(b1 + 8*j);
        float4 bb = *(const float4*)(b1 + 8*j + 4);
        h1[0]=ba.x; h1[1]=ba.y; h1[2]=ba.z; h1[3]=ba.w;
        h1[4]=bb.x; h1[5]=bb.y; h1[6]=bb.z; h1[7]=bb.w;
    }
#pragma unroll
    for (int d=0; d<20; ++d) {
        float4 w0 = *(const float4*)(w1 + d*32 + 8*j);
        float4 w4 = *(const float4*)(w1 + d*32 + 8*j + 4);
        float xv = x[d];
        h1[0] += xv*w0.x; h1[1] += xv*w0.y; h1[2] += xv*w0.z; h1[3] += xv*w0.w;
        h1[4] += xv*w4.x; h1[5] += xv*w4.y; h1[6] += xv*w4.z; h1[7] += xv*w4.w;
    }
#pragma unroll
    for (int o=0;o<8;++o) h1[o] = fmaxf(h1[o], 0.f);

    float s = 0.f;
#pragma unroll
    for (int half=0; half<2; ++half) {
        float p[16];
#pragma unroll
        for (int q=0;q<16;++q) p[q] = 0.f;
#pragma unroll
        for (int o=0;o<8;++o) {
            const float* row = w2 + (8*j + o)*32 + 16*half;
            float hv = h1[o];
#pragma unroll
            for (int q=0;q<4;++q) {
                float4 w = *(const float4*)(row + 4*q);
                p[4*q+0] += hv*w.x; p[4*q+1] += hv*w.y;
                p[4*q+2] += hv*w.z; p[4*q+3] += hv*w.w;
            }
        }
#pragma unroll
        for (int q=0;q<16;++q) { p[q] += __shfl_xor(p[q],1); p[q] += __shfl_xor(p[q],2); }
#pragma unroll
        for (int q=0;q<4;++q) {
            float4 bq = *(const float4*)(b2 + 16*half + 4*q);
            float4 wq = *(const float4*)(w3 + 16*half + 4*q);
            s += fmaxf(p[4*q+0]+bq.x, 0.f)*wq.x;
            s += fmaxf(p[4*q+1]+bq.y, 0.f)*wq.y;
            s += fmaxf(p[4*q+2]+bq.z, 0.f)*wq.z;
            s += fmaxf(p[4*q+3]+bq.w, 0.f)*wq.w;
        }
    }
    return s;
}

__global__ __launch_bounds__(256) void k_fused(
    const float* __restrict__ Smat, const float* __restrict__ Rraw, const float* __restrict__ Mspec,
    const float* __restrict__ We1, const float* __restrict__ be1,
    const float* __restrict__ We2, const float* __restrict__ be2,
    const float* __restrict__ Wf1, const float* __restrict__ bf1,
    const float* __restrict__ Wf2, const float* __restrict__ bf2,
    const float* __restrict__ Wf3, const float* __restrict__ bf3,
    const float* __restrict__ Wv1, const float* __restrict__ bv1,
    const float* __restrict__ Wv2, const float* __restrict__ bv2,
    const float* __restrict__ Wv3, const float* __restrict__ bv3,
    float* __restrict__ logits, float* __restrict__ pmax,
    float* __restrict__ psum, float* __restrict__ pval, int n)
{
    __shared__ __align__(16) float4 s_e1[10];
    __shared__ __align__(16) float  s_e2[10][12];
    __shared__ __align__(16) float  s_f1[640], s_v1[640];
    __shared__ __align__(16) float  s_f2[1024], s_v2[1024];
    __shared__ __align__(16) float  s_b1[32], s_b2[32], s_f3[32];
    __shared__ __align__(16) float  s_bv1[32], s_bv2[32], s_v3[32];
    __shared__ __align__(16) float  s_a0[64][16];
    __shared__ float red_l[64], red_v[64];

    const int tid = threadIdx.x;
    for (int i=tid;i<640;i+=256){ s_f1[i]=Wf1[i]; s_v1[i]=Wv1[i]; }
    for (int i=tid;i<1024;i+=256){ s_f2[i]=Wf2[i]; s_v2[i]=Wv2[i]; }
    if (tid<32){ s_b1[tid]=bf1[tid]; s_b2[tid]=bf2[tid]; s_f3[tid]=Wf3[tid];
                 s_bv1[tid]=bv1[tid]; s_bv2[tid]=bv2[tid]; s_v3[tid]=Wv3[tid]; }
    if (tid<10){
        s_e1[tid] = make_float4(be1[tid], We1[tid], We1[10+tid], We1[20+tid]);
        s_e2[tid][0] = be2[tid];
        for (int e=0;e<10;++e) s_e2[tid][1+e] = We2[e*10+tid];
        s_e2[tid][11] = 0.f;
    }
    __syncthreads();

    const int j    = tid & 3;
    const int grp  = tid >> 2;
    const int act  = blockIdx.x*64 + grp;
    const bool active = act < n;
    const int actc = active ? act : (n-1);

    const float*  sp = Smat + (size_t)actc*ATOM;
    const float4* rp = (const float4*)Rraw  + (size_t)actc*ATOM;
    const float4* mp = (const float4*)Mspec + (size_t)actc*48;

    float Bh[4][10];
    float Rsum[4] = {0.f,0.f,0.f,0.f};
#pragma unroll
    for (int l=0;l<4;++l)
#pragma unroll
        for (int e=0;e<10;++e) Bh[l][e]=0.f;

#pragma unroll 1
    for (int c=0;c<4;++c) {
        const int a0 = 16*j + 4*c;
        const float4 s4 = *(const float4*)(sp + a0);
        const float4 rv0 = rp[a0+0];
        const float4 rv1 = rp[a0+1];
        const float4 rv2 = rp[a0+2];
        const float4 rv3 = rp[a0+3];
        const float4 mA = mp[12*j+3*c+0];
        const float4 mB = mp[12*j+3*c+1];
        const float4 mC = mp[12*j+3*c+2];

        const float  sv[4]  = {s4.x,s4.y,s4.z,s4.w};
        const float4 rv[4]  = {rv0,rv1,rv2,rv3};
        const float  mk[12] = {mA.x,mA.y,mA.z,mA.w,mB.x,mB.y,mB.z,mB.w,mC.x,mC.y,mC.z,mC.w};

#pragma unroll
        for (int u=0;u<4;++u) {
            const float s   = sv[u];
            const float Rl0 = s*rv[u].x, Rl1 = s*rv[u].y, Rl2 = s*rv[u].z, Rl3 = s*rv[u].w;
            const float sg0 = s*mk[3*u+0], sg1 = s*mk[3*u+1], sg2 = s*mk[3*u+2];
            float h[10];
#pragma unroll
            for (int e=0;e<10;++e) {
                const float4 w = s_e1[e];
                h[e] = fmaxf(0.f, w.x + sg0*w.y + sg1*w.z + sg2*w.w);
            }
            Rsum[0]+=Rl0; Rsum[1]+=Rl1; Rsum[2]+=Rl2; Rsum[3]+=Rl3;
#pragma unroll
            for (int e=0;e<10;++e) {
                const float he = h[e];
                Bh[0][e]+=Rl0*he; Bh[1][e]+=Rl1*he; Bh[2][e]+=Rl2*he; Bh[3][e]+=Rl3*he;
            }
            if (c==0 && u==0 && j==0) {
#pragma unroll
                for (int e=0;e<10;++e) s_a0[grp][e]=h[e];
                s_a0[grp][10]=Rl0; s_a0[grp][11]=Rl1; s_a0[grp][12]=Rl2; s_a0[grp][13]=Rl3;
            }
        }
    }

#pragma unroll
    for (int l=0;l<4;++l) {
        float v=Rsum[l]; v+=__shfl_xor(v,1); v+=__shfl_xor(v,2); Rsum[l]=v;
#pragma unroll
        for (int e=0;e<10;++e) {
            float w=Bh[l][e]; w+=__shfl_xor(w,1); w+=__shfl_xor(w,2); Bh[l][e]=w;
        }
    }

    float Df[20];
    make_D(Bh, Rsum, s_e2, Df);
    {
        const float* a0p = &s_a0[grp][0];
#pragma unroll
        for (int l=0;l<4;++l) {
            const float r0 = a0p[10+l];
            Rsum[l] -= r0;
#pragma unroll
            for (int e=0;e<10;++e) Bh[l][e] -= r0*a0p[e];
        }
    }
    float Dv[20];
    make_D(Bh, Rsum, s_e2, Dv);

    const float logit = mlp_head_quad(Df, s_f1, s_b1, s_f2, s_b2, s_f3, j) + bf3[0];
    const float vout  = mlp_head_quad(Dv, s_v1, s_bv1, s_v2, s_bv2, s_v3, j) + bv3[0];

    if (j==0) {
        red_l[grp] = active ? logit : -INFINITY;
        red_v[grp] = active ? vout  : 0.f;
        if (active) logits[act] = logit;
    }
    __syncthreads();

    if (tid < 64) {
        float m = red_l[tid];
#pragma unroll
        for (int k=1;k<64;k<<=1) m = fmaxf(m, __shfl_xor(m,k));
        float e = expf(red_l[tid] - m);
        float ssum = e, vsum = red_v[tid];
#pragma unroll
        for (int k=1;k<64;k<<=1){ ssum += __shfl_xor(ssum,k); vsum += __shfl_xor(vsum,k); }
        if (tid==0){ pmax[blockIdx.x]=m; psum[blockIdx.x]=ssum; pval[blockIdx.x]=vsum; }
    }
}

// ===========================================================================
// Merge per-block partials -> logZ, value ; apply shift
// ===========================================================================
__global__ __launch_bounds__(256) void k_reduce(const float* __restrict__ pmax,
                                                const float* __restrict__ psum,
                                                const float* __restrict__ pval,
                                                int nb,
                                                float* __restrict__ logZ,
                                                float* __restrict__ value_out)
{
    __shared__ float sm[256];
    const int tid = threadIdx.x;
    float m = -INFINITY;
    for (int i=tid;i<nb;i+=256) m = fmaxf(m, pmax[i]);
    sm[tid]=m; __syncthreads();
    for (int s=128;s>0;s>>=1){ if (tid<s) sm[tid]=fmaxf(sm[tid],sm[tid+s]); __syncthreads(); }
    const float M = sm[0]; __syncthreads();

    float ssum=0.f, vsum=0.f;
    for (int i=tid;i<nb;i+=256){ ssum += psum[i]*expf(pmax[i]-M); vsum += pval[i]; }
    sm[tid]=ssum; __syncthreads();
    for (int s=128;s>0;s>>=1){ if (tid<s) sm[tid]+=sm[tid+s]; __syncthreads(); }
    const float S = sm[0]; __syncthreads();

    sm[tid]=vsum; __syncthreads();
    for (int s=128;s>0;s>>=1){ if (tid<s) sm[tid]+=sm[tid+s]; __syncthreads(); }
    if (tid==0){ *logZ = M + logf(S); *value_out = sm[0]; }
}

__global__ __launch_bounds__(256) void k_apply(const float* __restrict__ logits,
                                               const float* __restrict__ logZ,
                                               float* __restrict__ out, int n)
{
    const int i = blockIdx.x*256 + threadIdx.x;
    if (i < n) out[i] = logits[i] - logZ[0];
}

extern "C" void kernel_launch(void* const* d_in, const int* in_sizes, int n_in,
                              void* d_out, int out_size, void* d_ws, size_t ws_size,
                              hipStream_t stream)
{
    const float* Smat  = (const float*)d_in[0];
    const float* Rraw  = (const float*)d_in[1];
    const float* Mspec = (const float*)d_in[2];
    const float* We1 = (const float*)d_in[3];  const float* be1 = (const float*)d_in[4];
    const float* We2 = (const float*)d_in[5];  const float* be2 = (const float*)d_in[6];
    const float* Wf1 = (const float*)d_in[7];  const float* bf1 = (const float*)d_in[8];
    const float* Wf2 = (const float*)d_in[9];  const float* bf2 = (const float*)d_in[10];
    const float* Wf3 = (const float*)d_in[11]; const float* bf3 = (const float*)d_in[12];
    const float* Wv1 = (const float*)d_in[13]; const float* bv1 = (const float*)d_in[14];
    const float* Wv2 = (const float*)d_in[15]; const float* bv2 = (const float*)d_in[16];
    const float* Wv3 = (const float*)d_in[17]; const float* bv3 = (const float*)d_in[18];

    const int n   = in_sizes[0] / ATOM;
    const int nbE = (n + 31) / 32;            // k_embed blocks (32 actions each)
    const int nbF = (n + 63) / 64;            // k_fused blocks
    const int nbH = (n + 127) / 128;          // k_head blocks

    float* out = (float*)d_out;               // [n] policy, [1] value
    const size_t need_new = ((size_t)58*n + (size_t)n + 3*(size_t)nbH + 16) * sizeof(float);

    if (ws_size >= need_new) {
        float* ws     = (float*)d_ws;
        float* Vws    = ws;                    // [44*n]
        float* A0ws   = Vws + (size_t)44*n;    // [14*n]
        float* logits = A0ws + (size_t)14*n;   // [n]
        float* pmax   = logits + n;            // [nbH]
        float* psum   = pmax + nbH;            // [nbH]
        float* pval   = psum + nbH;            // [nbH]
        float* logZ   = pval + nbH;            // [1]

        k_embed<<<nbE, 256, 0, stream>>>(Smat, Rraw, Mspec, We1, be1, Vws, A0ws, n);
        k_head<<<nbH, 256, 0, stream>>>(Vws, A0ws, We2, be2,
                                        Wf1, bf1, Wf2, bf2, Wf3, bf3,
                                        Wv1, bv1, Wv2, bv2, Wv3, bv3,
                                        logits, pmax, psum, pval, n);
        k_reduce<<<1, 256, 0, stream>>>(pmax, psum, pval, nbH, logZ, out + n);
        k_apply<<<(n + 255)/256, 256, 0, stream>>>(logits, logZ, out, n);
    } else {
        float* ws     = (float*)d_ws;
        float* logits = ws;                    // [n]
        float* pmax   = ws + n;                // [nbF]
        float* psum   = pmax + nbF;            // [nbF]
        float* pval   = psum + nbF;            // [nbF]
        float* logZ   = pval + nbF;            // [1]

        k_fused<<<nbF, 256, 0, stream>>>(Smat, Rraw, Mspec,
                                         We1, be1, We2, be2,
                                         Wf1, bf1, Wf2, bf2, Wf3, bf3,
                                         Wv1, bv1, Wv2, bv2, Wv3, bv3,
                                         logits, pmax, psum, pval, n);
        k_reduce<<<1, 256, 0, stream>>>(pmax, psum, pval, nbF, logZ, out + n);
        k_apply<<<(n + 255)/256, 256, 0, stream>>>(logits, logZ, out, n);
    }
}